// Round 16
// baseline (69.517 us; speedup 1.0000x reference)
//
#include <hip/hip_runtime.h>
#include <hip/hip_bf16.h>
#include <hip/hip_fp16.h>

typedef __attribute__((ext_vector_type(8))) short short8;
typedef __attribute__((ext_vector_type(8))) _Float16 half8;
typedef __attribute__((ext_vector_type(4))) float f32x4;
typedef __attribute__((ext_vector_type(2))) float f32x2;

#define MAXNBR 128
#define ALPHA 0.2f

static __device__ __forceinline__ unsigned short f2h(float f) {
    return __half_as_ushort(__float2half(f));
}
static __device__ __forceinline__ float h2f(unsigned short u) {
    return __half2float(__ushort_as_half(u));
}

// ---------- K0: cvt x->f16 (1024) | W1->W1t transpose (128) | fold w_sdT (16) ----------
__global__ __launch_bounds__(256) void cvt(const float* __restrict__ x,
                                           unsigned short* __restrict__ xh,
                                           const float* __restrict__ W1,
                                           unsigned short* __restrict__ W1t,
                                           const float* __restrict__ a_src1,
                                           const float* __restrict__ a_dst1,
                                           unsigned short* __restrict__ w_sdT) {
    __shared__ float tile[64][65];
    int b = blockIdx.x, t = threadIdx.x;
    if (b < 1024) {                       // x: 8 elems/thread
        size_t base = (size_t)b * 2048 + t * 8;
        float4 v0 = *(const float4*)&x[base];
        float4 v1 = *(const float4*)&x[base + 4];
        short8 o;
        o[0] = f2h(v0.x); o[1] = f2h(v0.y); o[2] = f2h(v0.z); o[3] = f2h(v0.w);
        o[4] = f2h(v1.x); o[5] = f2h(v1.y); o[6] = f2h(v1.z); o[7] = f2h(v1.w);
        *(short8*)&xh[base] = o;
    } else if (b < 1152) {                // W1t: 128 tiles of 64x64
        int tb = b - 1024;
        int tk = (tb >> 4) * 64, tc = (tb & 15) * 64;
        int g = t >> 6, cx = t & 63;
        #pragma unroll
        for (int r = 0; r < 16; ++r)
            tile[g * 16 + r][cx] = W1[(size_t)(tk + g * 16 + r) * 1024 + tc + cx];
        __syncthreads();
        #pragma unroll
        for (int r = 0; r < 16; ++r)
            W1t[(size_t)(tc + g * 16 + r) * 512 + tk + cx] = f2h(tile[cx][g * 16 + r]);
    } else {                              // fold: w_sdT[c][k], c<8: src head c, c>=8: dst
        int id = (b - 1152) * 256 + t;    // [0, 4096)
        int k = id >> 3, h = id & 7;
        const float* wrow = W1 + (size_t)k * 1024 + h * 128;
        const float* as = a_src1 + h * 128;
        const float* ad = a_dst1 + h * 128;
        float s = 0.f, d = 0.f;
        #pragma unroll 8
        for (int o = 0; o < 128; o += 4) {
            float4 wv = *(const float4*)&wrow[o];
            float4 a4 = *(const float4*)&as[o];
            float4 d4 = *(const float4*)&ad[o];
            s += wv.x * a4.x + wv.y * a4.y + wv.z * a4.z + wv.w * a4.w;
            d += wv.x * d4.x + wv.y * d4.y + wv.z * d4.z + wv.w * d4.w;
        }
        w_sdT[h * 512 + k] = f2h(s);
        w_sdT[(h + 8) * 512 + k] = f2h(d);
    }
}

// ---------- K1: fused GEMM (512, swizzled, emits fp8 only) + parallel scan (4096) ----------
__global__ __launch_bounds__(256) void gemm_scan(const unsigned short* __restrict__ A,
                                                 const unsigned short* __restrict__ Bt,
                                                 unsigned char* __restrict__ h1q,
                                                 const float* __restrict__ adj,
                                                 int* __restrict__ nbr_idx,
                                                 int* __restrict__ nbr_cnt) {
    __shared__ unsigned short Asm[128 * 64];   // 16 KB
    __shared__ unsigned short Bsm[64 * 64];    //  8 KB
    __shared__ int wsum[4];
    int b = blockIdx.x;
    int tid = threadIdx.x;
    if (b < 512) {
        int lane = tid & 63;
        int w = tid >> 6;
        int wr = w >> 1, wc = w & 1;           // waves 2x2; wave tile 64x32
        int rowBase = (b & 31) * 128, colBase = (b >> 5) * 64;
        int lr = lane >> 3;                    // row-in-8-group
        int lcs = ((lane & 7) ^ lr) * 8;       // inverse-swizzled source chunk
        f32x4 acc[4][2] = {};
        for (int k0 = 0; k0 < 512; k0 += 64) {
            #pragma unroll
            for (int i = 0; i < 4; ++i) {
                int rA = i * 32 + w * 8;
                __builtin_amdgcn_global_load_lds(
                    (const __attribute__((address_space(1))) void*)&A[(size_t)(rowBase + rA + lr) * 512 + k0 + lcs],
                    (__attribute__((address_space(3))) void*)&Asm[rA * 64],
                    16, 0, 0);
            }
            #pragma unroll
            for (int i = 0; i < 2; ++i) {
                int rB = i * 32 + w * 8;
                __builtin_amdgcn_global_load_lds(
                    (const __attribute__((address_space(1))) void*)&Bt[(size_t)(colBase + rB + lr) * 512 + k0 + lcs],
                    (__attribute__((address_space(3))) void*)&Bsm[rB * 64],
                    16, 0, 0);
            }
            __syncthreads();
            #pragma unroll
            for (int kk = 0; kk < 64; kk += 32) {
                half8 af[4], bfv[2];
                int kf = kk + (lane >> 4) * 8;
                #pragma unroll
                for (int m = 0; m < 4; ++m) {
                    int R = wr * 64 + m * 16 + (lane & 15);
                    af[m] = *(const half8*)&Asm[R * 64 + (kf ^ ((R & 7) << 3))];
                }
                #pragma unroll
                for (int n = 0; n < 2; ++n) {
                    int R = wc * 32 + n * 16 + (lane & 15);
                    bfv[n] = *(const half8*)&Bsm[R * 64 + (kf ^ ((R & 7) << 3))];
                }
                #pragma unroll
                for (int m = 0; m < 4; ++m)
                    #pragma unroll
                    for (int n = 0; n < 2; ++n)
                        acc[m][n] = __builtin_amdgcn_mfma_f32_16x16x32_f16(af[m], bfv[n], acc[m][n], 0, 0, 0);
            }
            __syncthreads();
        }
        int crow0 = rowBase + wr * 64, ccol0 = colBase + wc * 32;
        #pragma unroll
        for (int m = 0; m < 4; ++m)
            #pragma unroll
            for (int n = 0; n < 2; ++n) {
                int col = ccol0 + n * 16 + (lane & 15);
                int row0 = crow0 + m * 16 + (lane >> 4) * 4;
                #pragma unroll
                for (int r = 0; r < 4; ++r) {
                    float v = acc[m][n][r];
                    int w8 = __builtin_amdgcn_cvt_pk_fp8_f32(v, v, 0, false);
                    h1q[(size_t)(row0 + r) * 1024 + col] = (unsigned char)w8;
                }
            }
    } else {
        // ----- parallel adjacency scan: one row per block, prefix-sum compaction -----
        int row = b - 512;
        int t = tid;
        const float* arow = adj + (size_t)row * 4096;
        const float4* ap = (const float4*)(arow + t * 16);
        float4 v0 = ap[0], v1 = ap[1], v2 = ap[2], v3 = ap[3];
        unsigned mask = 0;
        #pragma unroll
        for (int q = 0; q < 4; ++q) {
            if (((const float*)&v0)[q] > 0.f) mask |= 1u << q;
            if (((const float*)&v1)[q] > 0.f) mask |= 1u << (4 + q);
            if (((const float*)&v2)[q] > 0.f) mask |= 1u << (8 + q);
            if (((const float*)&v3)[q] > 0.f) mask |= 1u << (12 + q);
        }
        int mycnt = __popc(mask);
        int lane = t & 63, w = t >> 6;
        int incl = mycnt;
        #pragma unroll
        for (int d = 1; d < 64; d <<= 1) {
            int nn = __shfl_up(incl, d);
            if (lane >= d) incl += nn;
        }
        if (lane == 63) wsum[w] = incl;
        __syncthreads();
        int base = (w > 0 ? wsum[0] : 0) + (w > 1 ? wsum[1] : 0) + (w > 2 ? wsum[2] : 0);
        int pos = base + incl - mycnt;
        #pragma unroll
        for (int q = 0; q < 16; ++q) {
            if (mask & (1u << q)) {
                if (pos < MAXNBR) nbr_idx[row * MAXNBR + pos] = t * 16 + q;
                ++pos;
            }
        }
        if (t == 255) {
            int tot = base + incl;
            nbr_cnt[row] = tot < MAXNBR ? tot : MAXNBR;
        }
    }
}

// ---------- K2: coef_gemm — fsp/fdp = xh[16 rows x 512] @ w_sdT[16 x 512] ----------
// Standalone 256-block MFMA kernel (NOT fused into gemm_scan — rule #19).
// B operand read straight from global (16 KB w_sdT, L2-resident).
__global__ __launch_bounds__(256) void coef_gemm(const unsigned short* __restrict__ xh,
                                                 const unsigned short* __restrict__ w_sdT,
                                                 float* __restrict__ fsp,
                                                 float* __restrict__ fdp) {
    __shared__ float pred[4][256];                 // 4 KB
    int t = threadIdx.x, lane = t & 63, w = t >> 6;
    int rowBase = blockIdx.x * 16;
    f32x4 acc = {};
    int r0 = lane & 15, kg = (lane >> 4) * 8;
    #pragma unroll
    for (int kk = 0; kk < 128; kk += 32) {
        int k0 = w * 128 + kk;
        half8 af = *(const half8*)&xh[(size_t)(rowBase + r0) * 512 + k0 + kg];
        half8 bf = *(const half8*)&w_sdT[(size_t)r0 * 512 + k0 + kg];
        acc = __builtin_amdgcn_mfma_f32_16x16x32_f16(af, bf, acc, 0, 0, 0);
    }
    #pragma unroll
    for (int r = 0; r < 4; ++r)
        pred[w][((lane >> 4) * 4 + r) * 16 + (lane & 15)] = acc[r];
    __syncthreads();
    {
        int row = t >> 4, col = t & 15;
        float s = pred[0][t] + pred[1][t] + pred[2][t] + pred[3][t];
        int n = rowBase + row;
        if (col < 8) fsp[n * 8 + col] = s;
        else         fdp[n * 8 + col - 8] = s;
    }
}

// ---------- K3: aggregate8 — 2 nodes/block (512 thr), fp8 gather, 2-way parity ----------
__global__ __launch_bounds__(512) void aggregate8(const unsigned char* __restrict__ h1q,
                                                  const int* __restrict__ nbr_idx,
                                                  const int* __restrict__ nbr_cnt,
                                                  const float* __restrict__ fsp,
                                                  const float* __restrict__ fdp,
                                                  unsigned short* __restrict__ h1act) {
    __shared__ int nbrS[2][MAXNBR];
    __shared__ float e_s[2][8][MAXNBR];
    __shared__ _Float16 attwS[2][8][MAXNBR];
    __shared__ half8 partS[2][128];
    int t = threadIdx.x;
    int sub = t >> 8, tl = t & 255;
    int i = blockIdx.x * 2 + sub;
    int cnt = nbr_cnt[i];
    int* nbr = nbrS[sub];
    if (tl < MAXNBR) {
        int nb = (tl < cnt) ? nbr_idx[i * MAXNBR + tl] : 0;
        nbr[tl] = nb;
        if (tl < cnt) {
            float4 fs0 = *(const float4*)&fsp[i * 8];
            float4 fs1 = *(const float4*)&fsp[i * 8 + 4];
            float4 d0 = *(const float4*)&fdp[nb * 8];
            float4 d1 = *(const float4*)&fdp[nb * 8 + 4];
            float e0 = fs0.x + d0.x, e1 = fs0.y + d0.y, e2 = fs0.z + d0.z, e3 = fs0.w + d0.w;
            float e4 = fs1.x + d1.x, e5 = fs1.y + d1.y, e6 = fs1.z + d1.z, e7 = fs1.w + d1.w;
            e_s[sub][0][tl] = e0 > 0.f ? e0 : ALPHA * e0;
            e_s[sub][1][tl] = e1 > 0.f ? e1 : ALPHA * e1;
            e_s[sub][2][tl] = e2 > 0.f ? e2 : ALPHA * e2;
            e_s[sub][3][tl] = e3 > 0.f ? e3 : ALPHA * e3;
            e_s[sub][4][tl] = e4 > 0.f ? e4 : ALPHA * e4;
            e_s[sub][5][tl] = e5 > 0.f ? e5 : ALPHA * e5;
            e_s[sub][6][tl] = e6 > 0.f ? e6 : ALPHA * e6;
            e_s[sub][7][tl] = e7 > 0.f ? e7 : ALPHA * e7;
        } else {
            #pragma unroll
            for (int h = 0; h < 8; ++h) e_s[sub][h][tl] = -INFINITY;
        }
    }
    __syncthreads();
    {
        int h = tl >> 5, sl = tl & 31;
        float e[4];
        #pragma unroll
        for (int p = 0; p < 4; ++p) e[p] = e_s[sub][h][sl + p * 32];
        float m = fmaxf(fmaxf(e[0], e[1]), fmaxf(e[2], e[3]));
        #pragma unroll
        for (int off = 1; off < 32; off <<= 1) m = fmaxf(m, __shfl_xor(m, off));
        float wq[4], s = 0.f;
        #pragma unroll
        for (int p = 0; p < 4; ++p) {
            wq[p] = (e[p] == -INFINITY) ? 0.f : __expf(e[p] - m);
            s += wq[p];
        }
        #pragma unroll
        for (int off = 1; off < 32; off <<= 1) s += __shfl_xor(s, off);
        float inv = 1.f / s;
        #pragma unroll
        for (int p = 0; p < 4; ++p)
            attwS[sub][h][sl + p * 32] = (_Float16)(wq[p] * inv);
    }
    __syncthreads();
    int tf = tl & 127;
    int par = tl >> 7;
    int head = tf >> 4;
    const unsigned char* src = h1q + tf * 8;
    float acc[8] = {0.f, 0.f, 0.f, 0.f, 0.f, 0.f, 0.f, 0.f};
    int cntPad = (cnt + 1) & ~1;
    for (int j = par; j < cntPad; j += 2) {
        int nb = nbr[j];
        float wv = (float)attwS[sub][head][j];
        uint2 v = *(const uint2*)&src[(size_t)nb << 10];
        f32x2 p0 = __builtin_amdgcn_cvt_pk_f32_fp8((int)v.x, false);
        f32x2 p1 = __builtin_amdgcn_cvt_pk_f32_fp8((int)v.x, true);
        f32x2 p2 = __builtin_amdgcn_cvt_pk_f32_fp8((int)v.y, false);
        f32x2 p3 = __builtin_amdgcn_cvt_pk_f32_fp8((int)v.y, true);
        acc[0] += wv * p0[0]; acc[1] += wv * p0[1];
        acc[2] += wv * p1[0]; acc[3] += wv * p1[1];
        acc[4] += wv * p2[0]; acc[5] += wv * p2[1];
        acc[6] += wv * p3[0]; acc[7] += wv * p3[1];
    }
    if (par) {
        half8 st;
        #pragma unroll
        for (int q = 0; q < 8; ++q) st[q] = (_Float16)acc[q];
        partS[sub][tf] = st;
    }
    __syncthreads();
    if (!par) {
        half8 p0 = partS[sub][tf];
        short8 o;
        #pragma unroll
        for (int q = 0; q < 8; ++q) {
            float a = acc[q] + (float)p0[q];
            a = a > 0.f ? a : (__expf(a) - 1.f);
            o[q] = f2h(a);
        }
        *(short8*)&h1act[(size_t)i * 1024 + tf * 8] = o;
    }
}

// ---------- K4: layer2 — 256 blocks x 16 rows, 4-wave K-split MFMA ----------
__global__ __launch_bounds__(256) void layer2_mfma(const unsigned short* __restrict__ h1act,
                                                   const float* __restrict__ W2,
                                                   const float* __restrict__ a_src2,
                                                   const float* __restrict__ a_dst2,
                                                   float* __restrict__ h2,
                                                   float2* __restrict__ fsd2) {
    __shared__ unsigned short W2t[16 * 1032];
    __shared__ float pred[4][256];
    int t = threadIdx.x, lane = t & 63, w = t >> 6;
    int rowBase = blockIdx.x * 16;
    for (int idx = t; idx < 16384; idx += 256) {
        int k = idx >> 4, o = idx & 15;
        W2t[o * 1032 + k] = f2h(W2[idx]);
    }
    __syncthreads();
    f32x4 acc = {};
    int r0 = lane & 15, kg = (lane >> 4) * 8;
    #pragma unroll
    for (int kk = 0; kk < 256; kk += 32) {
        int k0 = w * 256 + kk;
        half8 af = *(const half8*)&h1act[(size_t)(rowBase + r0) * 1024 + k0 + kg];
        half8 bf = *(const half8*)&W2t[r0 * 1032 + k0 + kg];
        acc = __builtin_amdgcn_mfma_f32_16x16x32_f16(af, bf, acc, 0, 0, 0);
    }
    #pragma unroll
    for (int r = 0; r < 4; ++r)
        pred[w][((lane >> 4) * 4 + r) * 16 + (lane & 15)] = acc[r];
    __syncthreads();
    if (t < 256) {
        int row = t >> 4, col = t & 15;
        float s = pred[0][t] + pred[1][t] + pred[2][t] + pred[3][t];
        h2[(rowBase + row) * 16 + col] = s;
        float ps = s * a_src2[col];
        float pd = s * a_dst2[col];
        #pragma unroll
        for (int off = 1; off < 16; off <<= 1) {
            ps += __shfl_xor(ps, off);
            pd += __shfl_xor(pd, off);
        }
        if (col == 0) fsd2[rowBase + row] = make_float2(ps, pd);
    }
}

// ---------- K5: final_layer2 — 4 nodes/block, wave/node, barrier-free ----------
__global__ __launch_bounds__(256) void final_layer2(const float* __restrict__ h2,
                                                    const int* __restrict__ nbr_idx,
                                                    const int* __restrict__ nbr_cnt,
                                                    const float2* __restrict__ fsd2,
                                                    float* __restrict__ out) {
    __shared__ float attnS[4][MAXNBR];
    __shared__ int nbrS[4][MAXNBR];
    int t = threadIdx.x;
    int w = t >> 6, l = t & 63;
    int i = blockIdx.x * 4 + w;
    float* attn = attnS[w];
    int* nbr = nbrS[w];
    int cnt = nbr_cnt[i];
    float fsi = fsd2[i].x;
    #pragma unroll
    for (int j = l; j < MAXNBR; j += 64) {
        float e = -INFINITY;
        if (j < cnt) {
            int jj = nbr_idx[i * MAXNBR + j];
            nbr[j] = jj;
            float xv = fsi + fsd2[jj].y;
            e = xv > 0.f ? xv : ALPHA * xv;
        }
        attn[j] = e;
    }
    float m = fmaxf(attn[l], attn[l + 64]);
    #pragma unroll
    for (int off = 1; off < 64; off <<= 1) m = fmaxf(m, __shfl_xor(m, off));
    float s = 0.f;
    {
        float e0 = attn[l], e1 = attn[l + 64];
        if (e0 != -INFINITY) s += __expf(e0 - m);
        if (e1 != -INFINITY) s += __expf(e1 - m);
    }
    #pragma unroll
    for (int off = 1; off < 64; off <<= 1) s += __shfl_xor(s, off);
    #pragma unroll
    for (int j = l; j < MAXNBR; j += 64) {
        float e = attn[j];
        attn[j] = (e == -INFINITY) ? 0.f : __expf(e - m) / s;
    }
    int o = l & 15, p = l >> 4;
    float acc = 0.f;
    for (int j = p; j < cnt; j += 4)
        acc += attn[j] * h2[nbr[j] * 16 + o];
    acc += __shfl_xor(acc, 16);
    acc += __shfl_xor(acc, 32);
    if (l < 16) {
        float v = acc > 0.f ? acc : expm1f(acc);
        float mx = v;
        #pragma unroll
        for (int off = 1; off < 16; off <<= 1) mx = fmaxf(mx, __shfl_xor(mx, off));
        float se = __expf(v - mx);
        #pragma unroll
        for (int off = 1; off < 16; off <<= 1) se += __shfl_xor(se, off);
        out[i * 16 + l] = v - mx - logf(se);
    }
}

extern "C" void kernel_launch(void* const* d_in, const int* in_sizes, int n_in,
                              void* d_out, int out_size, void* d_ws, size_t ws_size,
                              hipStream_t stream) {
    const float* x      = (const float*)d_in[0];
    const float* adj    = (const float*)d_in[1];
    const float* W1     = (const float*)d_in[2];
    const float* a_src1 = (const float*)d_in[3];
    const float* a_dst1 = (const float*)d_in[4];
    const float* W2     = (const float*)d_in[5];
    const float* a_src2 = (const float*)d_in[6];
    const float* a_dst2 = (const float*)d_in[7];
    float* out = (float*)d_out;

    char* ws = (char*)d_ws;
    unsigned short* xh    = (unsigned short*)ws;                      // 4 MB
    unsigned short* w1t   = (unsigned short*)(ws + (4u << 20));       // 1 MB
    unsigned short* w_sdT = (unsigned short*)(ws + (5u << 20));       // 16 KB
    float* fsp   = (float*)(ws + (14u << 20));                        // 128 KB
    float* fdp   = (float*)(ws + (14u << 20) + (128u << 10));         // 128 KB
    float* h2    = (float*)(ws + (15u << 20));                        // 256 KB
    float2* fsd2 = (float2*)(ws + (15u << 20) + (256u << 10));        // 32 KB
    int* nbr_idx = (int*)(ws + (16u << 20));                          // 2 MB
    int* nbr_cnt = (int*)(ws + (18u << 20));                          // 16 KB
    unsigned short* h1act = (unsigned short*)(ws + (26u << 20));      // 8 MB
    unsigned char* h1q    = (unsigned char*)(ws + (34u << 20));       // 4 MB

    cvt<<<1168, 256, 0, stream>>>(x, xh, W1, w1t, a_src1, a_dst1, w_sdT);
    gemm_scan<<<4608, 256, 0, stream>>>(xh, w1t, h1q, adj, nbr_idx, nbr_cnt);
    coef_gemm<<<256, 256, 0, stream>>>(xh, w_sdT, fsp, fdp);
    aggregate8<<<2048, 512, 0, stream>>>(h1q, nbr_idx, nbr_cnt, fsp, fdp, h1act);
    layer2_mfma<<<256, 256, 0, stream>>>(h1act, W2, a_src2, a_dst2, h2, fsd2);
    final_layer2<<<1024, 256, 0, stream>>>(h2, nbr_idx, nbr_cnt, fsd2, out);
}

// Round 17
// 64.635 us; speedup vs baseline: 1.0755x; 1.0755x over previous
//
#include <hip/hip_runtime.h>
#include <hip/hip_bf16.h>
#include <hip/hip_fp16.h>

typedef __attribute__((ext_vector_type(8))) short short8;
typedef __attribute__((ext_vector_type(8))) _Float16 half8;
typedef __attribute__((ext_vector_type(4))) float f32x4;
typedef __attribute__((ext_vector_type(2))) float f32x2;

#define MAXNBR 128
#define ALPHA 0.2f

static __device__ __forceinline__ unsigned short f2h(float f) {
    return __half_as_ushort(__float2half(f));
}
static __device__ __forceinline__ float h2f(unsigned short u) {
    return __half2float(__ushort_as_half(u));
}

// ---------- K0: cvt x -> f16 (1024 blocks); W1 -> W1t via LDS tile transpose (128) ----------
__global__ __launch_bounds__(256) void cvt(const float* __restrict__ x,
                                           unsigned short* __restrict__ xh,
                                           const float* __restrict__ W1,
                                           unsigned short* __restrict__ W1t) {
    __shared__ float tile[64][65];
    int b = blockIdx.x, t = threadIdx.x;
    if (b < 1024) {                       // x: 8 elems/thread
        size_t base = (size_t)b * 2048 + t * 8;
        float4 v0 = *(const float4*)&x[base];
        float4 v1 = *(const float4*)&x[base + 4];
        short8 o;
        o[0] = f2h(v0.x); o[1] = f2h(v0.y); o[2] = f2h(v0.z); o[3] = f2h(v0.w);
        o[4] = f2h(v1.x); o[5] = f2h(v1.y); o[6] = f2h(v1.z); o[7] = f2h(v1.w);
        *(short8*)&xh[base] = o;
    } else {                              // W1t: 128 tiles of 64x64
        int tb = b - 1024;
        int tk = (tb >> 4) * 64, tc = (tb & 15) * 64;
        int g = t >> 6, cx = t & 63;
        #pragma unroll
        for (int r = 0; r < 16; ++r)
            tile[g * 16 + r][cx] = W1[(size_t)(tk + g * 16 + r) * 1024 + tc + cx];
        __syncthreads();
        #pragma unroll
        for (int r = 0; r < 16; ++r)
            W1t[(size_t)(tc + g * 16 + r) * 512 + tk + cx] = f2h(tile[cx][g * 16 + r]);
    }
}

// ---------- K1: fused GEMM (512, swizzled, emits f16 + fp8) + parallel scan (4096) ----------
__global__ __launch_bounds__(256) void gemm_scan(const unsigned short* __restrict__ A,
                                                 const unsigned short* __restrict__ Bt,
                                                 unsigned short* __restrict__ C,
                                                 unsigned char* __restrict__ h1q,
                                                 const float* __restrict__ adj,
                                                 int* __restrict__ nbr_idx,
                                                 int* __restrict__ nbr_cnt) {
    __shared__ unsigned short Asm[128 * 64];   // 16 KB
    __shared__ unsigned short Bsm[64 * 64];    //  8 KB
    __shared__ int wsum[4];
    int b = blockIdx.x;
    int tid = threadIdx.x;
    if (b < 512) {
        int lane = tid & 63;
        int w = tid >> 6;
        int wr = w >> 1, wc = w & 1;           // waves 2x2; wave tile 64x32
        int rowBase = (b & 31) * 128, colBase = (b >> 5) * 64;
        int lr = lane >> 3;                    // row-in-8-group
        int lcs = ((lane & 7) ^ lr) * 8;       // inverse-swizzled source chunk
        f32x4 acc[4][2] = {};
        for (int k0 = 0; k0 < 512; k0 += 64) {
            #pragma unroll
            for (int i = 0; i < 4; ++i) {
                int rA = i * 32 + w * 8;
                __builtin_amdgcn_global_load_lds(
                    (const __attribute__((address_space(1))) void*)&A[(size_t)(rowBase + rA + lr) * 512 + k0 + lcs],
                    (__attribute__((address_space(3))) void*)&Asm[rA * 64],
                    16, 0, 0);
            }
            #pragma unroll
            for (int i = 0; i < 2; ++i) {
                int rB = i * 32 + w * 8;
                __builtin_amdgcn_global_load_lds(
                    (const __attribute__((address_space(1))) void*)&Bt[(size_t)(colBase + rB + lr) * 512 + k0 + lcs],
                    (__attribute__((address_space(3))) void*)&Bsm[rB * 64],
                    16, 0, 0);
            }
            __syncthreads();
            #pragma unroll
            for (int kk = 0; kk < 64; kk += 32) {
                half8 af[4], bfv[2];
                int kf = kk + (lane >> 4) * 8;
                #pragma unroll
                for (int m = 0; m < 4; ++m) {
                    int R = wr * 64 + m * 16 + (lane & 15);
                    af[m] = *(const half8*)&Asm[R * 64 + (kf ^ ((R & 7) << 3))];
                }
                #pragma unroll
                for (int n = 0; n < 2; ++n) {
                    int R = wc * 32 + n * 16 + (lane & 15);
                    bfv[n] = *(const half8*)&Bsm[R * 64 + (kf ^ ((R & 7) << 3))];
                }
                #pragma unroll
                for (int m = 0; m < 4; ++m)
                    #pragma unroll
                    for (int n = 0; n < 2; ++n)
                        acc[m][n] = __builtin_amdgcn_mfma_f32_16x16x32_f16(af[m], bfv[n], acc[m][n], 0, 0, 0);
            }
            __syncthreads();
        }
        int crow0 = rowBase + wr * 64, ccol0 = colBase + wc * 32;
        #pragma unroll
        for (int m = 0; m < 4; ++m)
            #pragma unroll
            for (int n = 0; n < 2; ++n) {
                int col = ccol0 + n * 16 + (lane & 15);
                int row0 = crow0 + m * 16 + (lane >> 4) * 4;
                #pragma unroll
                for (int r = 0; r < 4; ++r) {
                    float v = acc[m][n][r];
                    C[(size_t)(row0 + r) * 1024 + col] = f2h(v);
                    int w8 = __builtin_amdgcn_cvt_pk_fp8_f32(v, v, 0, false);
                    h1q[(size_t)(row0 + r) * 1024 + col] = (unsigned char)w8;
                }
            }
    } else {
        // ----- parallel adjacency scan: one row per block, prefix-sum compaction -----
        int row = b - 512;
        int t = tid;
        const float* arow = adj + (size_t)row * 4096;
        const float4* ap = (const float4*)(arow + t * 16);
        float4 v0 = ap[0], v1 = ap[1], v2 = ap[2], v3 = ap[3];
        unsigned mask = 0;
        #pragma unroll
        for (int q = 0; q < 4; ++q) {
            if (((const float*)&v0)[q] > 0.f) mask |= 1u << q;
            if (((const float*)&v1)[q] > 0.f) mask |= 1u << (4 + q);
            if (((const float*)&v2)[q] > 0.f) mask |= 1u << (8 + q);
            if (((const float*)&v3)[q] > 0.f) mask |= 1u << (12 + q);
        }
        int mycnt = __popc(mask);
        int lane = t & 63, w = t >> 6;
        int incl = mycnt;
        #pragma unroll
        for (int d = 1; d < 64; d <<= 1) {
            int nn = __shfl_up(incl, d);
            if (lane >= d) incl += nn;
        }
        if (lane == 63) wsum[w] = incl;
        __syncthreads();
        int base = (w > 0 ? wsum[0] : 0) + (w > 1 ? wsum[1] : 0) + (w > 2 ? wsum[2] : 0);
        int pos = base + incl - mycnt;
        #pragma unroll
        for (int q = 0; q < 16; ++q) {
            if (mask & (1u << q)) {
                if (pos < MAXNBR) nbr_idx[row * MAXNBR + pos] = t * 16 + q;
                ++pos;
            }
        }
        if (t == 255) {
            int tot = base + incl;
            nbr_cnt[row] = tot < MAXNBR ? tot : MAXNBR;
        }
    }
}

// ---------- K2: attn_coef2 — 4 nodes/block, wave/node, 16 feats/lane ----------
__global__ __launch_bounds__(256) void attn_coef2(const unsigned short* __restrict__ h1h,
                                                  const float* __restrict__ a_src,
                                                  const float* __restrict__ a_dst,
                                                  float* __restrict__ fsp,
                                                  float* __restrict__ fdp) {
    int t = threadIdx.x;
    int n = blockIdx.x * 4 + (t >> 6);
    int l = t & 63;
    int head = l >> 3;
    const unsigned short* src = h1h + (size_t)n * 1024 + l * 16;
    const float* as = a_src + head * 128 + (l & 7) * 16;
    const float* ad = a_dst + head * 128 + (l & 7) * 16;
    float ps = 0.f, pd = 0.f;
    #pragma unroll
    for (int q = 0; q < 4; ++q) {
        ushort4 v = *(const ushort4*)&src[q * 4];
        float4 a4 = *(const float4*)&as[q * 4];
        float4 d4 = *(const float4*)&ad[q * 4];
        float h0 = h2f(v.x), h1 = h2f(v.y), h2_ = h2f(v.z), h3 = h2f(v.w);
        ps += h0 * a4.x + h1 * a4.y + h2_ * a4.z + h3 * a4.w;
        pd += h0 * d4.x + h1 * d4.y + h2_ * d4.z + h3 * d4.w;
    }
    ps += __shfl_xor(ps, 1); ps += __shfl_xor(ps, 2); ps += __shfl_xor(ps, 4);
    pd += __shfl_xor(pd, 1); pd += __shfl_xor(pd, 2); pd += __shfl_xor(pd, 4);
    if ((l & 7) == 0) {
        fsp[n * 8 + head] = ps;
        fdp[n * 8 + head] = pd;
    }
}

// ---------- K3: aggregate8 — 2 nodes/block (512 thr), fp8 gather, 2-way parity ----------
__global__ __launch_bounds__(512) void aggregate8(const unsigned char* __restrict__ h1q,
                                                  const int* __restrict__ nbr_idx,
                                                  const int* __restrict__ nbr_cnt,
                                                  const float* __restrict__ fsp,
                                                  const float* __restrict__ fdp,
                                                  unsigned short* __restrict__ h1act) {
    __shared__ int nbrS[2][MAXNBR];
    __shared__ float e_s[2][8][MAXNBR];
    __shared__ _Float16 attwS[2][8][MAXNBR];
    __shared__ half8 partS[2][128];
    int t = threadIdx.x;
    int sub = t >> 8, tl = t & 255;
    int i = blockIdx.x * 2 + sub;
    int cnt = nbr_cnt[i];
    int* nbr = nbrS[sub];
    if (tl < MAXNBR) {
        int nb = (tl < cnt) ? nbr_idx[i * MAXNBR + tl] : 0;
        nbr[tl] = nb;
        if (tl < cnt) {
            float4 fs0 = *(const float4*)&fsp[i * 8];
            float4 fs1 = *(const float4*)&fsp[i * 8 + 4];
            float4 d0 = *(const float4*)&fdp[nb * 8];
            float4 d1 = *(const float4*)&fdp[nb * 8 + 4];
            float e0 = fs0.x + d0.x, e1 = fs0.y + d0.y, e2 = fs0.z + d0.z, e3 = fs0.w + d0.w;
            float e4 = fs1.x + d1.x, e5 = fs1.y + d1.y, e6 = fs1.z + d1.z, e7 = fs1.w + d1.w;
            e_s[sub][0][tl] = e0 > 0.f ? e0 : ALPHA * e0;
            e_s[sub][1][tl] = e1 > 0.f ? e1 : ALPHA * e1;
            e_s[sub][2][tl] = e2 > 0.f ? e2 : ALPHA * e2;
            e_s[sub][3][tl] = e3 > 0.f ? e3 : ALPHA * e3;
            e_s[sub][4][tl] = e4 > 0.f ? e4 : ALPHA * e4;
            e_s[sub][5][tl] = e5 > 0.f ? e5 : ALPHA * e5;
            e_s[sub][6][tl] = e6 > 0.f ? e6 : ALPHA * e6;
            e_s[sub][7][tl] = e7 > 0.f ? e7 : ALPHA * e7;
        } else {
            #pragma unroll
            for (int h = 0; h < 8; ++h) e_s[sub][h][tl] = -INFINITY;
        }
    }
    __syncthreads();
    {
        int h = tl >> 5, sl = tl & 31;
        float e[4];
        #pragma unroll
        for (int p = 0; p < 4; ++p) e[p] = e_s[sub][h][sl + p * 32];
        float m = fmaxf(fmaxf(e[0], e[1]), fmaxf(e[2], e[3]));
        #pragma unroll
        for (int off = 1; off < 32; off <<= 1) m = fmaxf(m, __shfl_xor(m, off));
        float wq[4], s = 0.f;
        #pragma unroll
        for (int p = 0; p < 4; ++p) {
            wq[p] = (e[p] == -INFINITY) ? 0.f : __expf(e[p] - m);
            s += wq[p];
        }
        #pragma unroll
        for (int off = 1; off < 32; off <<= 1) s += __shfl_xor(s, off);
        float inv = 1.f / s;
        #pragma unroll
        for (int p = 0; p < 4; ++p)
            attwS[sub][h][sl + p * 32] = (_Float16)(wq[p] * inv);
    }
    __syncthreads();
    int tf = tl & 127;
    int par = tl >> 7;
    int head = tf >> 4;
    const unsigned char* src = h1q + tf * 8;
    float acc[8] = {0.f, 0.f, 0.f, 0.f, 0.f, 0.f, 0.f, 0.f};
    int cntPad = (cnt + 1) & ~1;
    for (int j = par; j < cntPad; j += 2) {
        int nb = nbr[j];
        float wv = (float)attwS[sub][head][j];
        uint2 v = *(const uint2*)&src[(size_t)nb << 10];
        f32x2 p0 = __builtin_amdgcn_cvt_pk_f32_fp8((int)v.x, false);
        f32x2 p1 = __builtin_amdgcn_cvt_pk_f32_fp8((int)v.x, true);
        f32x2 p2 = __builtin_amdgcn_cvt_pk_f32_fp8((int)v.y, false);
        f32x2 p3 = __builtin_amdgcn_cvt_pk_f32_fp8((int)v.y, true);
        acc[0] += wv * p0[0]; acc[1] += wv * p0[1];
        acc[2] += wv * p1[0]; acc[3] += wv * p1[1];
        acc[4] += wv * p2[0]; acc[5] += wv * p2[1];
        acc[6] += wv * p3[0]; acc[7] += wv * p3[1];
    }
    if (par) {
        half8 st;
        #pragma unroll
        for (int q = 0; q < 8; ++q) st[q] = (_Float16)acc[q];
        partS[sub][tf] = st;
    }
    __syncthreads();
    if (!par) {
        half8 p0 = partS[sub][tf];
        short8 o;
        #pragma unroll
        for (int q = 0; q < 8; ++q) {
            float a = acc[q] + (float)p0[q];
            a = a > 0.f ? a : (__expf(a) - 1.f);
            o[q] = f2h(a);
        }
        *(short8*)&h1act[(size_t)i * 1024 + tf * 8] = o;
    }
}

// ---------- K4: layer2 — 256 blocks x 16 rows, 4-wave K-split MFMA ----------
__global__ __launch_bounds__(256) void layer2_mfma(const unsigned short* __restrict__ h1act,
                                                   const float* __restrict__ W2,
                                                   const float* __restrict__ a_src2,
                                                   const float* __restrict__ a_dst2,
                                                   float* __restrict__ h2,
                                                   float2* __restrict__ fsd2) {
    __shared__ unsigned short W2t[16 * 1032];
    __shared__ float pred[4][256];
    int t = threadIdx.x, lane = t & 63, w = t >> 6;
    int rowBase = blockIdx.x * 16;
    for (int idx = t; idx < 16384; idx += 256) {
        int k = idx >> 4, o = idx & 15;
        W2t[o * 1032 + k] = f2h(W2[idx]);
    }
    __syncthreads();
    f32x4 acc = {};
    int r0 = lane & 15, kg = (lane >> 4) * 8;
    #pragma unroll
    for (int kk = 0; kk < 256; kk += 32) {
        int k0 = w * 256 + kk;
        half8 af = *(const half8*)&h1act[(size_t)(rowBase + r0) * 1024 + k0 + kg];
        half8 bf = *(const half8*)&W2t[r0 * 1032 + k0 + kg];
        acc = __builtin_amdgcn_mfma_f32_16x16x32_f16(af, bf, acc, 0, 0, 0);
    }
    #pragma unroll
    for (int r = 0; r < 4; ++r)
        pred[w][((lane >> 4) * 4 + r) * 16 + (lane & 15)] = acc[r];
    __syncthreads();
    if (t < 256) {
        int row = t >> 4, col = t & 15;
        float s = pred[0][t] + pred[1][t] + pred[2][t] + pred[3][t];
        h2[(rowBase + row) * 16 + col] = s;
        float ps = s * a_src2[col];
        float pd = s * a_dst2[col];
        #pragma unroll
        for (int off = 1; off < 16; off <<= 1) {
            ps += __shfl_xor(ps, off);
            pd += __shfl_xor(pd, off);
        }
        if (col == 0) fsd2[rowBase + row] = make_float2(ps, pd);
    }
}

// ---------- K5: final_layer2 — 4 nodes/block, wave/node, barrier-free ----------
__global__ __launch_bounds__(256) void final_layer2(const float* __restrict__ h2,
                                                    const int* __restrict__ nbr_idx,
                                                    const int* __restrict__ nbr_cnt,
                                                    const float2* __restrict__ fsd2,
                                                    float* __restrict__ out) {
    __shared__ float attnS[4][MAXNBR];
    __shared__ int nbrS[4][MAXNBR];
    int t = threadIdx.x;
    int w = t >> 6, l = t & 63;
    int i = blockIdx.x * 4 + w;
    float* attn = attnS[w];
    int* nbr = nbrS[w];
    int cnt = nbr_cnt[i];
    float fsi = fsd2[i].x;
    #pragma unroll
    for (int j = l; j < MAXNBR; j += 64) {
        float e = -INFINITY;
        if (j < cnt) {
            int jj = nbr_idx[i * MAXNBR + j];
            nbr[j] = jj;
            float xv = fsi + fsd2[jj].y;
            e = xv > 0.f ? xv : ALPHA * xv;
        }
        attn[j] = e;
    }
    float m = fmaxf(attn[l], attn[l + 64]);
    #pragma unroll
    for (int off = 1; off < 64; off <<= 1) m = fmaxf(m, __shfl_xor(m, off));
    float s = 0.f;
    {
        float e0 = attn[l], e1 = attn[l + 64];
        if (e0 != -INFINITY) s += __expf(e0 - m);
        if (e1 != -INFINITY) s += __expf(e1 - m);
    }
    #pragma unroll
    for (int off = 1; off < 64; off <<= 1) s += __shfl_xor(s, off);
    #pragma unroll
    for (int j = l; j < MAXNBR; j += 64) {
        float e = attn[j];
        attn[j] = (e == -INFINITY) ? 0.f : __expf(e - m) / s;
    }
    int o = l & 15, p = l >> 4;
    float acc = 0.f;
    for (int j = p; j < cnt; j += 4)
        acc += attn[j] * h2[nbr[j] * 16 + o];
    acc += __shfl_xor(acc, 16);
    acc += __shfl_xor(acc, 32);
    if (l < 16) {
        float v = acc > 0.f ? acc : expm1f(acc);
        float mx = v;
        #pragma unroll
        for (int off = 1; off < 16; off <<= 1) mx = fmaxf(mx, __shfl_xor(mx, off));
        float se = __expf(v - mx);
        #pragma unroll
        for (int off = 1; off < 16; off <<= 1) se += __shfl_xor(se, off);
        out[i * 16 + l] = v - mx - logf(se);
    }
}

extern "C" void kernel_launch(void* const* d_in, const int* in_sizes, int n_in,
                              void* d_out, int out_size, void* d_ws, size_t ws_size,
                              hipStream_t stream) {
    const float* x      = (const float*)d_in[0];
    const float* adj    = (const float*)d_in[1];
    const float* W1     = (const float*)d_in[2];
    const float* a_src1 = (const float*)d_in[3];
    const float* a_dst1 = (const float*)d_in[4];
    const float* W2     = (const float*)d_in[5];
    const float* a_src2 = (const float*)d_in[6];
    const float* a_dst2 = (const float*)d_in[7];
    float* out = (float*)d_out;

    char* ws = (char*)d_ws;
    unsigned short* xh    = (unsigned short*)ws;                      // 4 MB
    unsigned short* w1t   = (unsigned short*)(ws + (4u << 20));       // 1 MB
    unsigned short* h1h   = (unsigned short*)(ws + (6u << 20));       // 8 MB
    float* fsp   = (float*)(ws + (14u << 20));                        // 128 KB
    float* fdp   = (float*)(ws + (14u << 20) + (128u << 10));         // 128 KB
    float* h2    = (float*)(ws + (15u << 20));                        // 256 KB
    float2* fsd2 = (float2*)(ws + (15u << 20) + (256u << 10));        // 32 KB
    int* nbr_idx = (int*)(ws + (16u << 20));                          // 2 MB
    int* nbr_cnt = (int*)(ws + (18u << 20));                          // 16 KB
    unsigned short* h1act = (unsigned short*)(ws + (26u << 20));      // 8 MB
    unsigned char* h1q    = (unsigned char*)(ws + (34u << 20));       // 4 MB

    cvt<<<1152, 256, 0, stream>>>(x, xh, W1, w1t);
    gemm_scan<<<4608, 256, 0, stream>>>(xh, w1t, h1h, h1q, adj, nbr_idx, nbr_cnt);
    attn_coef2<<<1024, 256, 0, stream>>>(h1h, a_src1, a_dst1, fsp, fdp);
    aggregate8<<<2048, 512, 0, stream>>>(h1q, nbr_idx, nbr_cnt, fsp, fdp, h1act);
    layer2_mfma<<<256, 256, 0, stream>>>(h1act, W2, a_src2, a_dst2, h2, fsd2);
    final_layer2<<<1024, 256, 0, stream>>>(h2, nbr_idx, nbr_cnt, fsd2, out);
}